// Round 1
// baseline (609.523 us; speedup 1.0000x reference)
//
#include <hip/hip_runtime.h>
#include <hip/hip_bf16.h>

#define FEAT 128
#define NRELS 16

using short8 = __attribute__((ext_vector_type(8))) short;
using f32x4  = __attribute__((ext_vector_type(4))) float;

__device__ inline ushort f2bf(float x) {
    union { float f; unsigned int u; } v; v.f = x;
    unsigned int u = v.u;
    // round-to-nearest-even
    unsigned int r = (u + 0x7fffu + ((u >> 16) & 1u)) >> 16;
    return (ushort)r;
}
__device__ inline float bf2f(ushort b) {
    union { unsigned int u; float f; } v; v.u = ((unsigned int)b) << 16;
    return v.f;
}

// ---------------------------------------------------------------------------
// Kernel 1: proj[r][n][:] = h[n][:] @ W[r]   (bf16 MFMA, f32 accumulate)
// grid: (NBLK, rc). Each block owns one relation, stages W^T in LDS once,
// then strides over 64-row chunks of h.
// ---------------------------------------------------------------------------
constexpr int BM = 64;

__global__ __launch_bounds__(256) void proj_kernel(
    const float* __restrict__ h, const float* __restrict__ W,
    ushort* __restrict__ proj, int n_nodes, int r0)
{
    __shared__ ushort Wt[128][136];  // Wt[n][k] = W[k][n], +8 pad kills read conflicts
    __shared__ ushort hs[BM][136];   // hs[m][k]

    const int tid  = threadIdx.x;
    const int rel  = r0 + blockIdx.y;
    const float* Wg = W + (size_t)rel * FEAT * FEAT;

    // Stage W transposed -> bf16 LDS (once per block, amortized over chunks)
    #pragma unroll
    for (int it = 0; it < 16; ++it) {
        int f = (it * 256 + tid) * 4;          // flat over 128*128
        int k = f >> 7, n = f & 127;
        float4 w4 = *reinterpret_cast<const float4*>(Wg + f);
        Wt[n + 0][k] = f2bf(w4.x);
        Wt[n + 1][k] = f2bf(w4.y);
        Wt[n + 2][k] = f2bf(w4.z);
        Wt[n + 3][k] = f2bf(w4.w);
    }

    const int lane = tid & 63;
    const int wave = tid >> 6;       // 0..3 -> row sub-block
    const int r    = lane & 15;
    const int kgrp = lane >> 4;      // 0..3

    ushort* projr = proj + (size_t)blockIdx.y * n_nodes * FEAT;
    const int nchunks = (n_nodes + BM - 1) / BM;

    for (int c = blockIdx.x; c < nchunks; c += gridDim.x) {
        const int m0 = c * BM;
        __syncthreads();             // hs reuse guard (also covers Wt 1st iter)
        // stage 64 rows of h -> bf16 LDS
        #pragma unroll
        for (int it = 0; it < 8; ++it) {
            int f = (it * 256 + tid) * 4;      // flat over 64*128
            int m = f >> 7, k = f & 127;
            int row = m0 + m;
            float4 v = make_float4(0.f, 0.f, 0.f, 0.f);
            if (row < n_nodes)
                v = *reinterpret_cast<const float4*>(h + (size_t)row * FEAT + k);
            ushort4 u;
            u.x = f2bf(v.x); u.y = f2bf(v.y); u.z = f2bf(v.z); u.w = f2bf(v.w);
            *reinterpret_cast<ushort4*>(&hs[m][k]) = u;
        }
        __syncthreads();

        f32x4 acc[8];
        #pragma unroll
        for (int i = 0; i < 8; ++i) acc[i] = f32x4{0.f, 0.f, 0.f, 0.f};

        #pragma unroll
        for (int kk = 0; kk < 4; ++kk) {
            const int kbase = kk * 32 + kgrp * 8;
            short8 a = *reinterpret_cast<const short8*>(&hs[wave * 16 + r][kbase]);
            #pragma unroll
            for (int ct = 0; ct < 8; ++ct) {
                short8 b = *reinterpret_cast<const short8*>(&Wt[ct * 16 + r][kbase]);
                acc[ct] = __builtin_amdgcn_mfma_f32_16x16x32_bf16(a, b, acc[ct], 0, 0, 0);
            }
        }

        // D layout: col = lane&15, row = (lane>>4)*4 + i   [m89-verified]
        #pragma unroll
        for (int ct = 0; ct < 8; ++ct) {
            #pragma unroll
            for (int i = 0; i < 4; ++i) {
                int row = m0 + wave * 16 + kgrp * 4 + i;
                if (row < n_nodes)
                    projr[(size_t)row * FEAT + ct * 16 + r] = f2bf(acc[ct][i]);
            }
        }
    }
}

// ---------------------------------------------------------------------------
// Kernel 2: per edge, out[dst] += proj[rel, src] * norm  (one wave per edge)
// ---------------------------------------------------------------------------
__global__ __launch_bounds__(256) void edge_kernel(
    const ushort* __restrict__ proj, const float* __restrict__ norm,
    const int* __restrict__ src, const int* __restrict__ dst,
    const int* __restrict__ rel, float* __restrict__ out,
    int n_edges, int n_nodes, int r0, int r1)
{
    const int lane = threadIdx.x & 63;
    int gw = (int)((blockIdx.x * blockDim.x + threadIdx.x) >> 6);
    const int nw = (int)((gridDim.x * blockDim.x) >> 6);

    for (int e = gw; e < n_edges; e += nw) {
        int rr = rel[e];
        if (rr < r0 || rr >= r1) continue;
        int s = src[e];
        int d = dst[e];
        float nm = norm[e];
        const ushort* prow = proj + ((size_t)(rr - r0) * n_nodes + s) * FEAT;
        unsigned int v = *reinterpret_cast<const unsigned int*>(prow + lane * 2);
        float x0 = bf2f((ushort)(v & 0xffffu)) * nm;
        float x1 = bf2f((ushort)(v >> 16)) * nm;
        float* o = out + (size_t)d * FEAT + lane * 2;
        atomicAdd(o + 0, x0);
        atomicAdd(o + 1, x1);
    }
}

// ---------------------------------------------------------------------------
// Kernel 3: in-place ReLU
// ---------------------------------------------------------------------------
__global__ __launch_bounds__(256) void relu_kernel(float4* out, int n4)
{
    int i = blockIdx.x * blockDim.x + threadIdx.x;
    int stride = gridDim.x * blockDim.x;
    for (; i < n4; i += stride) {
        float4 v = out[i];
        v.x = fmaxf(v.x, 0.f);
        v.y = fmaxf(v.y, 0.f);
        v.z = fmaxf(v.z, 0.f);
        v.w = fmaxf(v.w, 0.f);
        out[i] = v;
    }
}

extern "C" void kernel_launch(void* const* d_in, const int* in_sizes, int n_in,
                              void* d_out, int out_size, void* d_ws, size_t ws_size,
                              hipStream_t stream)
{
    const float* h    = (const float*)d_in[0];
    const float* W    = (const float*)d_in[1];
    const float* norm = (const float*)d_in[2];
    const int*   src  = (const int*)d_in[3];
    const int*   dst  = (const int*)d_in[4];
    const int*   rel  = (const int*)d_in[5];
    float* out = (float*)d_out;

    const int n_nodes = in_sizes[0] / FEAT;   // 20000
    const int n_edges = in_sizes[3];          // 640000
    ushort* proj = (ushort*)d_ws;

    // out is poisoned by the harness -> zero it (atomic accumulation target)
    hipMemsetAsync(out, 0, (size_t)out_size * sizeof(float), stream);

    // Fit proj (bf16, [rc, n_nodes, FEAT]) into workspace; chunk relations if needed
    const size_t perRel = (size_t)n_nodes * FEAT * sizeof(ushort);
    int rc = NRELS;
    if (ws_size < perRel * NRELS) {
        rc = (int)(ws_size / perRel);
        if (rc < 1) rc = 1;
        if (rc > NRELS) rc = NRELS;
    }

    for (int r0 = 0; r0 < NRELS; r0 += rc) {
        const int rcc = (rc < NRELS - r0) ? rc : (NRELS - r0);
        dim3 g1(32, rcc);
        proj_kernel<<<g1, 256, 0, stream>>>(h, W, proj, n_nodes, r0);
        edge_kernel<<<1024, 256, 0, stream>>>(proj, norm, src, dst, rel, out,
                                              n_edges, n_nodes, r0, r0 + rcc);
    }
    relu_kernel<<<2048, 256, 0, stream>>>((float4*)out, out_size / 4);
}

// Round 2
// 216.497 us; speedup vs baseline: 2.8154x; 2.8154x over previous
//
#include <hip/hip_runtime.h>
#include <hip/hip_bf16.h>

#define FEAT 128
#define NRELS 16

using short8 = __attribute__((ext_vector_type(8))) short;
using f32x4  = __attribute__((ext_vector_type(4))) float;

__device__ inline ushort f2bf(float x) {
    union { float f; unsigned int u; } v; v.f = x;
    unsigned int u = v.u;
    unsigned int r = (u + 0x7fffu + ((u >> 16) & 1u)) >> 16;  // RNE
    return (ushort)r;
}
__device__ inline float bf2f(ushort b) {
    union { unsigned int u; float f; } v; v.u = ((unsigned int)b) << 16;
    return v.f;
}

// ---------------------------------------------------------------------------
// Kernel 1: proj[r][n][:] = h[n][:] @ W[r]   (bf16 MFMA, f32 accumulate)
// ---------------------------------------------------------------------------
constexpr int BM = 64;

__global__ __launch_bounds__(256) void proj_kernel(
    const float* __restrict__ h, const float* __restrict__ W,
    ushort* __restrict__ proj, int n_nodes, int r0)
{
    __shared__ ushort Wt[128][136];
    __shared__ ushort hs[BM][136];

    const int tid  = threadIdx.x;
    const int rel  = r0 + blockIdx.y;
    const float* Wg = W + (size_t)rel * FEAT * FEAT;

    #pragma unroll
    for (int it = 0; it < 16; ++it) {
        int f = (it * 256 + tid) * 4;
        int k = f >> 7, n = f & 127;
        float4 w4 = *reinterpret_cast<const float4*>(Wg + f);
        Wt[n + 0][k] = f2bf(w4.x);
        Wt[n + 1][k] = f2bf(w4.y);
        Wt[n + 2][k] = f2bf(w4.z);
        Wt[n + 3][k] = f2bf(w4.w);
    }

    const int lane = tid & 63;
    const int wave = tid >> 6;
    const int r    = lane & 15;
    const int kgrp = lane >> 4;

    ushort* projr = proj + (size_t)blockIdx.y * n_nodes * FEAT;
    const int nchunks = (n_nodes + BM - 1) / BM;

    for (int c = blockIdx.x; c < nchunks; c += gridDim.x) {
        const int m0 = c * BM;
        __syncthreads();
        #pragma unroll
        for (int it = 0; it < 8; ++it) {
            int f = (it * 256 + tid) * 4;
            int m = f >> 7, k = f & 127;
            int row = m0 + m;
            float4 v = make_float4(0.f, 0.f, 0.f, 0.f);
            if (row < n_nodes)
                v = *reinterpret_cast<const float4*>(h + (size_t)row * FEAT + k);
            ushort4 u;
            u.x = f2bf(v.x); u.y = f2bf(v.y); u.z = f2bf(v.z); u.w = f2bf(v.w);
            *reinterpret_cast<ushort4*>(&hs[m][k]) = u;
        }
        __syncthreads();

        f32x4 acc[8];
        #pragma unroll
        for (int i = 0; i < 8; ++i) acc[i] = f32x4{0.f, 0.f, 0.f, 0.f};

        #pragma unroll
        for (int kk = 0; kk < 4; ++kk) {
            const int kbase = kk * 32 + kgrp * 8;
            short8 a = *reinterpret_cast<const short8*>(&hs[wave * 16 + r][kbase]);
            #pragma unroll
            for (int ct = 0; ct < 8; ++ct) {
                short8 b = *reinterpret_cast<const short8*>(&Wt[ct * 16 + r][kbase]);
                acc[ct] = __builtin_amdgcn_mfma_f32_16x16x32_bf16(a, b, acc[ct], 0, 0, 0);
            }
        }

        #pragma unroll
        for (int ct = 0; ct < 8; ++ct) {
            #pragma unroll
            for (int i = 0; i < 4; ++i) {
                int row = m0 + wave * 16 + kgrp * 4 + i;
                if (row < n_nodes)
                    projr[(size_t)row * FEAT + ct * 16 + r] = f2bf(acc[ct][i]);
            }
        }
    }
}

// ---------------------------------------------------------------------------
// CSR build: histogram -> scan -> scatter
// ---------------------------------------------------------------------------
__global__ __launch_bounds__(256) void hist_kernel(
    const int* __restrict__ dst, int* __restrict__ cnt, int n_edges)
{
    int i = blockIdx.x * blockDim.x + threadIdx.x;
    int stride = gridDim.x * blockDim.x;
    for (; i < n_edges; i += stride)
        atomicAdd(&cnt[dst[i]], 1);
}

__global__ __launch_bounds__(1024) void scan_kernel(
    const int* __restrict__ cnt, int* __restrict__ off,
    int* __restrict__ cursor, int n)
{
    __shared__ int part[1024];
    const int tid = threadIdx.x;
    const int chunk = (n + 1023) / 1024;
    int s = 0;
    for (int i = 0; i < chunk; ++i) {
        int idx = tid * chunk + i;
        if (idx < n) s += cnt[idx];
    }
    part[tid] = s;
    __syncthreads();
    // Hillis-Steele inclusive scan
    for (int d = 1; d < 1024; d <<= 1) {
        int v = (tid >= d) ? part[tid - d] : 0;
        __syncthreads();
        part[tid] += v;
        __syncthreads();
    }
    int run = (tid > 0) ? part[tid - 1] : 0;   // exclusive prefix
    for (int i = 0; i < chunk; ++i) {
        int idx = tid * chunk + i;
        if (idx < n) {
            off[idx] = run;
            cursor[idx] = run;
            run += cnt[idx];
        }
    }
    if (tid == 1023) off[n] = part[1023];
}

__global__ __launch_bounds__(256) void scatter_kernel(
    const int* __restrict__ src, const int* __restrict__ dst,
    const int* __restrict__ rel, const float* __restrict__ norm,
    int* __restrict__ cursor, uint2* __restrict__ recs, int n_edges)
{
    int i = blockIdx.x * blockDim.x + threadIdx.x;
    int stride = gridDim.x * blockDim.x;
    for (; i < n_edges; i += stride) {
        int p = atomicAdd(&cursor[dst[i]], 1);
        uint2 r;
        r.x = (unsigned)src[i] | ((unsigned)rel[i] << 16);
        r.y = __float_as_uint(norm[i]);
        recs[p] = r;
    }
}

// ---------------------------------------------------------------------------
// Gather: one wave per dst node. No atomics; fused ReLU.
// ---------------------------------------------------------------------------
__global__ __launch_bounds__(256) void gather_kernel(
    const ushort* __restrict__ proj, const uint2* __restrict__ recs,
    const int* __restrict__ off, float* __restrict__ out, int n_nodes)
{
    const int wid  = (int)((blockIdx.x * blockDim.x + threadIdx.x) >> 6);
    const int lane = threadIdx.x & 63;
    if (wid >= n_nodes) return;

    const int beg = off[wid];
    const int end = off[wid + 1];

    float a0 = 0.f, a1 = 0.f;
    for (int base = beg; base < end; base += 64) {
        const int n = min(64, end - base);
        uint2 r = (base + lane < end) ? recs[base + lane] : make_uint2(0u, 0u);
        for (int j = 0; j < n; ++j) {
            unsigned key = (unsigned)__shfl((int)r.x, j);
            float nm = __uint_as_float((unsigned)__shfl((int)r.y, j));
            int s  = key & 0xffffu;
            int rr = key >> 16;
            const ushort* prow = proj + ((size_t)rr * n_nodes + s) * FEAT;
            unsigned v = *reinterpret_cast<const unsigned*>(prow + lane * 2);
            a0 += bf2f((ushort)(v & 0xffffu)) * nm;
            a1 += bf2f((ushort)(v >> 16)) * nm;
        }
    }
    float2 o;
    o.x = fmaxf(a0, 0.f);
    o.y = fmaxf(a1, 0.f);
    *reinterpret_cast<float2*>(out + (size_t)wid * FEAT + lane * 2) = o;
}

// ---------------------------------------------------------------------------
// Fallback path (small ws): atomic edge kernel + relu (previous version)
// ---------------------------------------------------------------------------
__global__ __launch_bounds__(256) void edge_kernel(
    const ushort* __restrict__ proj, const float* __restrict__ norm,
    const int* __restrict__ src, const int* __restrict__ dst,
    const int* __restrict__ rel, float* __restrict__ out,
    int n_edges, int n_nodes, int r0, int r1)
{
    const int lane = threadIdx.x & 63;
    int gw = (int)((blockIdx.x * blockDim.x + threadIdx.x) >> 6);
    const int nw = (int)((gridDim.x * blockDim.x) >> 6);

    for (int e = gw; e < n_edges; e += nw) {
        int rr = rel[e];
        if (rr < r0 || rr >= r1) continue;
        int s = src[e];
        int d = dst[e];
        float nm = norm[e];
        const ushort* prow = proj + ((size_t)(rr - r0) * n_nodes + s) * FEAT;
        unsigned int v = *reinterpret_cast<const unsigned int*>(prow + lane * 2);
        float x0 = bf2f((ushort)(v & 0xffffu)) * nm;
        float x1 = bf2f((ushort)(v >> 16)) * nm;
        float* o = out + (size_t)d * FEAT + lane * 2;
        atomicAdd(o + 0, x0);
        atomicAdd(o + 1, x1);
    }
}

__global__ __launch_bounds__(256) void relu_kernel(float4* out, int n4)
{
    int i = blockIdx.x * blockDim.x + threadIdx.x;
    int stride = gridDim.x * blockDim.x;
    for (; i < n4; i += stride) {
        float4 v = out[i];
        v.x = fmaxf(v.x, 0.f);
        v.y = fmaxf(v.y, 0.f);
        v.z = fmaxf(v.z, 0.f);
        v.w = fmaxf(v.w, 0.f);
        out[i] = v;
    }
}

extern "C" void kernel_launch(void* const* d_in, const int* in_sizes, int n_in,
                              void* d_out, int out_size, void* d_ws, size_t ws_size,
                              hipStream_t stream)
{
    const float* h    = (const float*)d_in[0];
    const float* W    = (const float*)d_in[1];
    const float* norm = (const float*)d_in[2];
    const int*   src  = (const int*)d_in[3];
    const int*   dst  = (const int*)d_in[4];
    const int*   rel  = (const int*)d_in[5];
    float* out = (float*)d_out;

    const int n_nodes = in_sizes[0] / FEAT;   // 20000
    const int n_edges = in_sizes[3];          // 640000

    // ws layout for the sorted path
    const size_t projB   = (size_t)NRELS * n_nodes * FEAT * sizeof(ushort);
    const size_t recsOff = (projB + 255) & ~(size_t)255;
    const size_t recsB   = (size_t)n_edges * sizeof(uint2);
    const size_t cntOff  = (recsOff + recsB + 255) & ~(size_t)255;
    const size_t cntB    = ((size_t)(n_nodes + 1) * 4 + 255) & ~(size_t)255;
    const size_t offOff  = cntOff + cntB;
    const size_t curOff  = offOff + cntB;
    const size_t need    = curOff + cntB;

    if (ws_size >= need) {
        ushort* proj  = (ushort*)d_ws;
        uint2*  recs  = (uint2*)((char*)d_ws + recsOff);
        int*    cnt   = (int*)((char*)d_ws + cntOff);
        int*    offs  = (int*)((char*)d_ws + offOff);
        int*    curs  = (int*)((char*)d_ws + curOff);

        dim3 g1(32, NRELS);
        proj_kernel<<<g1, 256, 0, stream>>>(h, W, proj, n_nodes, 0);

        hipMemsetAsync(cnt, 0, (size_t)(n_nodes + 1) * 4, stream);
        hist_kernel<<<1024, 256, 0, stream>>>(dst, cnt, n_edges);
        scan_kernel<<<1, 1024, 0, stream>>>(cnt, offs, curs, n_nodes);
        scatter_kernel<<<1024, 256, 0, stream>>>(src, dst, rel, norm, curs, recs, n_edges);

        const int nblocks = (n_nodes * 64 + 255) / 256;
        gather_kernel<<<nblocks, 256, 0, stream>>>(proj, recs, offs, out, n_nodes);
    } else {
        // fallback: relation-chunked atomic path
        ushort* proj = (ushort*)d_ws;
        hipMemsetAsync(out, 0, (size_t)out_size * sizeof(float), stream);
        const size_t perRel = (size_t)n_nodes * FEAT * sizeof(ushort);
        int rc = (int)(ws_size / perRel);
        if (rc < 1) rc = 1;
        if (rc > NRELS) rc = NRELS;
        for (int r0 = 0; r0 < NRELS; r0 += rc) {
            const int rcc = (rc < NRELS - r0) ? rc : (NRELS - r0);
            dim3 g1(32, rcc);
            proj_kernel<<<g1, 256, 0, stream>>>(h, W, proj, n_nodes, r0);
            edge_kernel<<<1024, 256, 0, stream>>>(proj, norm, src, dst, rel, out,
                                                  n_edges, n_nodes, r0, r0 + rcc);
        }
        relu_kernel<<<2048, 256, 0, stream>>>((float4*)out, out_size / 4);
    }
}

// Round 3
// 200.599 us; speedup vs baseline: 3.0385x; 1.0793x over previous
//
#include <hip/hip_runtime.h>
#include <hip/hip_bf16.h>

#define FEAT 128
#define NRELS 16

using short8 = __attribute__((ext_vector_type(8))) short;
using f32x4  = __attribute__((ext_vector_type(4))) float;

__device__ inline ushort f2bf(float x) {
    union { float f; unsigned int u; } v; v.f = x;
    unsigned int u = v.u;
    unsigned int r = (u + 0x7fffu + ((u >> 16) & 1u)) >> 16;  // RNE
    return (ushort)r;
}
__device__ inline float bf2f(ushort b) {
    union { unsigned int u; float f; } v; v.u = ((unsigned int)b) << 16;
    return v.f;
}

// ---------------------------------------------------------------------------
// Pack h -> bf16 MFMA A-slabs. Slab layout (short8 units):
//   hpack[(mblk*4 + ks)*64 + lane][j] = h[mblk*16 + (lane&15)][ks*32 + (lane>>4)*8 + j]
// ---------------------------------------------------------------------------
__global__ __launch_bounds__(256) void pack_h_kernel(
    const float* __restrict__ h, ushort* __restrict__ hpack, int n_nodes, int nmblk)
{
    int t = blockIdx.x * 256 + threadIdx.x;            // == (mblk*4+ks)*64 + lane
    if (t >= nmblk * 256) return;
    int lane = t & 63;
    int ks   = (t >> 6) & 3;
    int mblk = t >> 8;
    int row  = mblk * 16 + (lane & 15);
    int k0   = ks * 32 + (lane >> 4) * 8;

    ushort u[8] = {0, 0, 0, 0, 0, 0, 0, 0};
    if (row < n_nodes) {
        const float* p = h + (size_t)row * FEAT + k0;
        float4 a = *reinterpret_cast<const float4*>(p);
        float4 b = *reinterpret_cast<const float4*>(p + 4);
        u[0] = f2bf(a.x); u[1] = f2bf(a.y); u[2] = f2bf(a.z); u[3] = f2bf(a.w);
        u[4] = f2bf(b.x); u[5] = f2bf(b.y); u[6] = f2bf(b.z); u[7] = f2bf(b.w);
    }
    *reinterpret_cast<short8*>(hpack + (size_t)t * 8) = *reinterpret_cast<short8*>(u);
}

// ---------------------------------------------------------------------------
// Pack W^T -> bf16 MFMA slabs (slab rows = OUTPUT FEATURE index):
//   wpack[((r*8+fb)*4 + ks)*64 + lane][j] = W[r][ks*32+(lane>>4)*8+j][fb*16+(lane&15)]
// ---------------------------------------------------------------------------
__global__ __launch_bounds__(256) void pack_w_kernel(
    const float* __restrict__ W, ushort* __restrict__ wpack)
{
    int t = blockIdx.x * 256 + threadIdx.x;            // == ((r*8+fb)*4+ks)*64 + lane
    if (t >= NRELS * 8 * 4 * 64) return;
    int lane = t & 63;
    int ks   = (t >> 6) & 3;
    int fb   = (t >> 8) & 7;
    int r    = t >> 11;
    int k0   = ks * 32 + (lane >> 4) * 8;
    int f    = fb * 16 + (lane & 15);

    ushort u[8];
    #pragma unroll
    for (int j = 0; j < 8; ++j)
        u[j] = f2bf(W[((size_t)r * FEAT + (k0 + j)) * FEAT + f]);
    *reinterpret_cast<short8*>(wpack + (size_t)t * 8) = *reinterpret_cast<short8*>(u);
}

// ---------------------------------------------------------------------------
// proj[r][n][f] = h[n][:] @ W[r][:][f]  -- no LDS, no barriers.
// Wave owns one rel (all 128 feats, W-frags register-resident), grid-strides
// over 16-node chunks. D = mfma(Wfrag, hfrag):
//   feature_in_fb = (l>>4)*4 + i  (in-lane contiguous -> ushort4 8B stores)
//   node          = l&15
// ---------------------------------------------------------------------------
__global__ __launch_bounds__(256) void proj2_kernel(
    const ushort* __restrict__ hpack, const ushort* __restrict__ wpack,
    ushort* __restrict__ proj, int n_nodes, int nmblk)
{
    const int lane = threadIdx.x & 63;
    const int wv   = threadIdx.x >> 6;
    const int rr   = blockIdx.y;

    const short8* wp = reinterpret_cast<const short8*>(wpack);
    const short8* hp = reinterpret_cast<const short8*>(hpack);

    short8 X[8][4];
    #pragma unroll
    for (int fb = 0; fb < 8; ++fb)
        #pragma unroll
        for (int ks = 0; ks < 4; ++ks)
            X[fb][ks] = wp[(((rr * 8 + fb) * 4 + ks) << 6) + lane];

    const int wgid    = blockIdx.x * 4 + wv;
    const int wstride = gridDim.x * 4;

    for (int mb = wgid; mb < nmblk; mb += wstride) {
        short8 Y[4];
        #pragma unroll
        for (int ks = 0; ks < 4; ++ks)
            Y[ks] = hp[((mb * 4 + ks) << 6) + lane];

        f32x4 acc[8];
        #pragma unroll
        for (int fb = 0; fb < 8; ++fb) acc[fb] = f32x4{0.f, 0.f, 0.f, 0.f};

        #pragma unroll
        for (int ks = 0; ks < 4; ++ks)
            #pragma unroll
            for (int fb = 0; fb < 8; ++fb)
                acc[fb] = __builtin_amdgcn_mfma_f32_16x16x32_bf16(X[fb][ks], Y[ks], acc[fb], 0, 0, 0);

        const int node = mb * 16 + (lane & 15);
        if (node < n_nodes) {
            ushort* prow = proj + ((size_t)rr * n_nodes + node) * FEAT + (lane >> 4) * 4;
            #pragma unroll
            for (int fb = 0; fb < 8; ++fb) {
                unsigned d0 = (unsigned)f2bf(acc[fb][0]) | ((unsigned)f2bf(acc[fb][1]) << 16);
                unsigned d1 = (unsigned)f2bf(acc[fb][2]) | ((unsigned)f2bf(acc[fb][3]) << 16);
                uint2 d; d.x = d0; d.y = d1;
                *reinterpret_cast<uint2*>(prow + fb * 16) = d;
            }
        }
    }
}

// ---------------------------------------------------------------------------
// CSR build: histogram -> scan -> scatter
// ---------------------------------------------------------------------------
__global__ __launch_bounds__(256) void hist_kernel(
    const int* __restrict__ dst, int* __restrict__ cnt, int n_edges)
{
    int i = blockIdx.x * blockDim.x + threadIdx.x;
    int stride = gridDim.x * blockDim.x;
    for (; i < n_edges; i += stride)
        atomicAdd(&cnt[dst[i]], 1);
}

__global__ __launch_bounds__(1024) void scan_kernel(
    const int* __restrict__ cnt, int* __restrict__ off,
    int* __restrict__ cursor, int n)
{
    __shared__ int part[1024];
    const int tid = threadIdx.x;
    const int chunk = (n + 1023) / 1024;
    int s = 0;
    for (int i = 0; i < chunk; ++i) {
        int idx = tid * chunk + i;
        if (idx < n) s += cnt[idx];
    }
    part[tid] = s;
    __syncthreads();
    for (int d = 1; d < 1024; d <<= 1) {
        int v = (tid >= d) ? part[tid - d] : 0;
        __syncthreads();
        part[tid] += v;
        __syncthreads();
    }
    int run = (tid > 0) ? part[tid - 1] : 0;
    for (int i = 0; i < chunk; ++i) {
        int idx = tid * chunk + i;
        if (idx < n) {
            off[idx] = run;
            cursor[idx] = run;
            run += cnt[idx];
        }
    }
    if (tid == 1023) off[n] = part[1023];
}

__global__ __launch_bounds__(256) void scatter_kernel(
    const int* __restrict__ src, const int* __restrict__ dst,
    const int* __restrict__ rel, const float* __restrict__ norm,
    int* __restrict__ cursor, uint2* __restrict__ recs, int n_edges)
{
    int i = blockIdx.x * blockDim.x + threadIdx.x;
    int stride = gridDim.x * blockDim.x;
    for (; i < n_edges; i += stride) {
        int p = atomicAdd(&cursor[dst[i]], 1);
        uint2 r;
        r.x = (unsigned)src[i] | ((unsigned)rel[i] << 16);
        r.y = __float_as_uint(norm[i]);
        recs[p] = r;
    }
}

// ---------------------------------------------------------------------------
// Gather: 2 nodes per wave (32 lanes x 4 feats), 1-deep prefetch, fused ReLU.
// ---------------------------------------------------------------------------
__global__ __launch_bounds__(256) void gather_kernel(
    const ushort* __restrict__ proj, const uint2* __restrict__ recs,
    const int* __restrict__ off, float* __restrict__ out, int n_nodes)
{
    const int gw   = (int)((blockIdx.x * blockDim.x + threadIdx.x) >> 6);
    const int half = (threadIdx.x >> 5) & 1;
    const int hl   = threadIdx.x & 31;
    const int node = gw * 2 + half;
    if (node >= n_nodes) return;

    const int beg = off[node];
    const int end = off[node + 1];

    float a0 = 0.f, a1 = 0.f, a2 = 0.f, a3 = 0.f;
    for (int base = beg; base < end; base += 32) {
        const int n = min(32, end - base);
        uint2 r = (base + hl < end) ? recs[base + hl] : make_uint2(0u, 0u);

        unsigned key = (unsigned)__shfl((int)r.x, 0, 32);
        float    nm  = __uint_as_float((unsigned)__shfl((int)r.y, 0, 32));
        const ushort* prow = proj + ((size_t)(key >> 16) * n_nodes + (key & 0xffffu)) * FEAT;
        uint2 v = *reinterpret_cast<const uint2*>(prow + hl * 4);

        for (int j = 0; j < n; ++j) {
            uint2 vc = v;
            float nmc = nm;
            if (j + 1 < n) {
                unsigned key2 = (unsigned)__shfl((int)r.x, j + 1, 32);
                nm = __uint_as_float((unsigned)__shfl((int)r.y, j + 1, 32));
                const ushort* prow2 = proj + ((size_t)(key2 >> 16) * n_nodes + (key2 & 0xffffu)) * FEAT;
                v = *reinterpret_cast<const uint2*>(prow2 + hl * 4);
            }
            a0 += bf2f((ushort)(vc.x & 0xffffu)) * nmc;
            a1 += bf2f((ushort)(vc.x >> 16)) * nmc;
            a2 += bf2f((ushort)(vc.y & 0xffffu)) * nmc;
            a3 += bf2f((ushort)(vc.y >> 16)) * nmc;
        }
    }
    float4 o;
    o.x = fmaxf(a0, 0.f);
    o.y = fmaxf(a1, 0.f);
    o.z = fmaxf(a2, 0.f);
    o.w = fmaxf(a3, 0.f);
    *reinterpret_cast<float4*>(out + (size_t)node * FEAT + hl * 4) = o;
}

// ---------------------------------------------------------------------------
// Fallback proj (LDS version) + atomic edge path
// ---------------------------------------------------------------------------
constexpr int BM = 64;

__global__ __launch_bounds__(256) void proj_kernel(
    const float* __restrict__ h, const float* __restrict__ W,
    ushort* __restrict__ proj, int n_nodes, int r0)
{
    __shared__ ushort Wt[128][136];
    __shared__ ushort hs[BM][136];

    const int tid  = threadIdx.x;
    const int rel  = r0 + blockIdx.y;
    const float* Wg = W + (size_t)rel * FEAT * FEAT;

    #pragma unroll
    for (int it = 0; it < 16; ++it) {
        int f = (it * 256 + tid) * 4;
        int k = f >> 7, n = f & 127;
        float4 w4 = *reinterpret_cast<const float4*>(Wg + f);
        Wt[n + 0][k] = f2bf(w4.x);
        Wt[n + 1][k] = f2bf(w4.y);
        Wt[n + 2][k] = f2bf(w4.z);
        Wt[n + 3][k] = f2bf(w4.w);
    }

    const int lane = tid & 63;
    const int wave = tid >> 6;
    const int r    = lane & 15;
    const int kgrp = lane >> 4;

    ushort* projr = proj + (size_t)blockIdx.y * n_nodes * FEAT;
    const int nchunks = (n_nodes + BM - 1) / BM;

    for (int c = blockIdx.x; c < nchunks; c += gridDim.x) {
        const int m0 = c * BM;
        __syncthreads();
        #pragma unroll
        for (int it = 0; it < 8; ++it) {
            int f = (it * 256 + tid) * 4;
            int m = f >> 7, k = f & 127;
            int row = m0 + m;
            float4 v = make_float4(0.f, 0.f, 0.f, 0.f);
            if (row < n_nodes)
                v = *reinterpret_cast<const float4*>(h + (size_t)row * FEAT + k);
            ushort4 u;
            u.x = f2bf(v.x); u.y = f2bf(v.y); u.z = f2bf(v.z); u.w = f2bf(v.w);
            *reinterpret_cast<ushort4*>(&hs[m][k]) = u;
        }
        __syncthreads();

        f32x4 acc[8];
        #pragma unroll
        for (int i = 0; i < 8; ++i) acc[i] = f32x4{0.f, 0.f, 0.f, 0.f};

        #pragma unroll
        for (int kk = 0; kk < 4; ++kk) {
            const int kbase = kk * 32 + kgrp * 8;
            short8 a = *reinterpret_cast<const short8*>(&hs[wave * 16 + r][kbase]);
            #pragma unroll
            for (int ct = 0; ct < 8; ++ct) {
                short8 b = *reinterpret_cast<const short8*>(&Wt[ct * 16 + r][kbase]);
                acc[ct] = __builtin_amdgcn_mfma_f32_16x16x32_bf16(a, b, acc[ct], 0, 0, 0);
            }
        }

        #pragma unroll
        for (int ct = 0; ct < 8; ++ct) {
            #pragma unroll
            for (int i = 0; i < 4; ++i) {
                int row = m0 + wave * 16 + kgrp * 4 + i;
                if (row < n_nodes)
                    projr[(size_t)row * FEAT + ct * 16 + r] = f2bf(acc[ct][i]);
            }
        }
    }
}

__global__ __launch_bounds__(256) void edge_kernel(
    const ushort* __restrict__ proj, const float* __restrict__ norm,
    const int* __restrict__ src, const int* __restrict__ dst,
    const int* __restrict__ rel, float* __restrict__ out,
    int n_edges, int n_nodes, int r0, int r1)
{
    const int lane = threadIdx.x & 63;
    int gw = (int)((blockIdx.x * blockDim.x + threadIdx.x) >> 6);
    const int nw = (int)((gridDim.x * blockDim.x) >> 6);

    for (int e = gw; e < n_edges; e += nw) {
        int rr = rel[e];
        if (rr < r0 || rr >= r1) continue;
        int s = src[e];
        int d = dst[e];
        float nm = norm[e];
        const ushort* prow = proj + ((size_t)(rr - r0) * n_nodes + s) * FEAT;
        unsigned int v = *reinterpret_cast<const unsigned int*>(prow + lane * 2);
        float x0 = bf2f((ushort)(v & 0xffffu)) * nm;
        float x1 = bf2f((ushort)(v >> 16)) * nm;
        float* o = out + (size_t)d * FEAT + lane * 2;
        atomicAdd(o + 0, x0);
        atomicAdd(o + 1, x1);
    }
}

__global__ __launch_bounds__(256) void relu_kernel(float4* out, int n4)
{
    int i = blockIdx.x * blockDim.x + threadIdx.x;
    int stride = gridDim.x * blockDim.x;
    for (; i < n4; i += stride) {
        float4 v = out[i];
        v.x = fmaxf(v.x, 0.f);
        v.y = fmaxf(v.y, 0.f);
        v.z = fmaxf(v.z, 0.f);
        v.w = fmaxf(v.w, 0.f);
        out[i] = v;
    }
}

extern "C" void kernel_launch(void* const* d_in, const int* in_sizes, int n_in,
                              void* d_out, int out_size, void* d_ws, size_t ws_size,
                              hipStream_t stream)
{
    const float* h    = (const float*)d_in[0];
    const float* W    = (const float*)d_in[1];
    const float* norm = (const float*)d_in[2];
    const int*   src  = (const int*)d_in[3];
    const int*   dst  = (const int*)d_in[4];
    const int*   rel  = (const int*)d_in[5];
    float* out = (float*)d_out;

    const int n_nodes = in_sizes[0] / FEAT;   // 20000
    const int n_edges = in_sizes[3];          // 640000
    const int nmblk   = (n_nodes + 15) / 16;

    // ws layout
    const size_t projB   = (size_t)NRELS * n_nodes * FEAT * sizeof(ushort);
    const size_t recsOff = (projB + 255) & ~(size_t)255;
    const size_t recsB   = (size_t)n_edges * sizeof(uint2);
    const size_t cntOff  = (recsOff + recsB + 255) & ~(size_t)255;
    const size_t cntB    = ((size_t)(n_nodes + 1) * 4 + 255) & ~(size_t)255;
    const size_t offOff  = cntOff + cntB;
    const size_t curOff  = offOff + cntB;
    const size_t sortedNeed = curOff + cntB;
    const size_t hpackOff = (sortedNeed + 255) & ~(size_t)255;
    const size_t hpackB  = (size_t)nmblk * 256 * 8 * sizeof(ushort);
    const size_t wpackOff = (hpackOff + hpackB + 255) & ~(size_t)255;
    const size_t wpackB  = (size_t)NRELS * 8 * 4 * 64 * 8 * sizeof(ushort);
    const size_t packedNeed = wpackOff + wpackB;

    if (ws_size >= sortedNeed) {
        ushort* proj  = (ushort*)d_ws;
        uint2*  recs  = (uint2*)((char*)d_ws + recsOff);
        int*    cnt   = (int*)((char*)d_ws + cntOff);
        int*    offs  = (int*)((char*)d_ws + offOff);
        int*    curs  = (int*)((char*)d_ws + curOff);

        if (ws_size >= packedNeed) {
            ushort* hpack = (ushort*)((char*)d_ws + hpackOff);
            ushort* wpack = (ushort*)((char*)d_ws + wpackOff);
            pack_h_kernel<<<nmblk, 256, 0, stream>>>(h, hpack, n_nodes, nmblk);
            pack_w_kernel<<<(NRELS * 8 * 4 * 64 + 255) / 256, 256, 0, stream>>>(W, wpack);
            dim3 g1(128, NRELS);
            proj2_kernel<<<g1, 256, 0, stream>>>(hpack, wpack, proj, n_nodes, nmblk);
        } else {
            dim3 g1(32, NRELS);
            proj_kernel<<<g1, 256, 0, stream>>>(h, W, proj, n_nodes, 0);
        }

        hipMemsetAsync(cnt, 0, (size_t)(n_nodes + 1) * 4, stream);
        hist_kernel<<<1024, 256, 0, stream>>>(dst, cnt, n_edges);
        scan_kernel<<<1, 1024, 0, stream>>>(cnt, offs, curs, n_nodes);
        scatter_kernel<<<1024, 256, 0, stream>>>(src, dst, rel, norm, curs, recs, n_edges);

        const int nwaves = (n_nodes + 1) / 2;
        const int nblocks = (nwaves * 64 + 255) / 256;
        gather_kernel<<<nblocks, 256, 0, stream>>>(proj, recs, offs, out, n_nodes);
    } else {
        ushort* proj = (ushort*)d_ws;
        hipMemsetAsync(out, 0, (size_t)out_size * sizeof(float), stream);
        const size_t perRel = (size_t)n_nodes * FEAT * sizeof(ushort);
        int rc = (int)(ws_size / perRel);
        if (rc < 1) rc = 1;
        if (rc > NRELS) rc = NRELS;
        for (int r0 = 0; r0 < NRELS; r0 += rc) {
            const int rcc = (rc < NRELS - r0) ? rc : (NRELS - r0);
            dim3 g1(32, rcc);
            proj_kernel<<<g1, 256, 0, stream>>>(h, W, proj, n_nodes, r0);
            edge_kernel<<<1024, 256, 0, stream>>>(proj, norm, src, dst, rel, out,
                                                  n_edges, n_nodes, r0, r0 + rcc);
        }
        relu_kernel<<<2048, 256, 0, stream>>>((float4*)out, out_size / 4);
    }
}